// Round 1
// baseline (1841.562 us; speedup 1.0000x reference)
//
#include <hip/hip_runtime.h>

// Problem constants (from reference setup_inputs)
#define B 4
#define C 3
#define H 1024
#define W 1024
#define N (H * W)
#define EPS 1e-8f

// Scatter kernel: one thread per (b, source-pixel n).
// Accumulates num into out[b,c,:] and den into den[b,:] via fp32 atomics.
__global__ __launch_bounds__(256) void splat_kernel(
    const float* __restrict__ im0,   // [B,C,H,W]
    const float* __restrict__ grid,  // [B,H,W,2]
    float* __restrict__ out,         // [B,C,H,W] used as numerator accumulator
    float* __restrict__ den)         // [B,H,W]
{
    int t = blockIdx.x * blockDim.x + threadIdx.x;
    if (t >= B * N) return;
    int b = t >> 20;          // t / N   (N = 1<<20)
    int n = t & (N - 1);      // t % N

    // grid is [B,H,W,2] interleaved -> float2 coalesced load
    const float2 g = ((const float2*)grid)[t];
    float x = g.x, y = g.y;

    float x0f = floorf(x);
    float y0f = floorf(y);
    float dx = x - x0f;
    float dy = y - y0f;
    int x0 = (int)x0f;
    int y0 = (int)y0f;

    // source pixel values, 3 channels (coalesced per channel)
    const float* imb = im0 + (size_t)b * C * N + n;
    float v0 = imb[0];
    float v1 = imb[N];
    float v2 = imb[2 * N];

    float* outb = out + (size_t)b * C * N;
    float* denb = den + (size_t)b * N;

    float wx[2] = {1.0f - dx, dx};
    float wy[2] = {1.0f - dy, dy};

#pragma unroll
    for (int cy = 0; cy < 2; ++cy) {
#pragma unroll
        for (int cx = 0; cx < 2; ++cx) {
            int xi = x0 + cx;
            int yi = y0 + cy;
            if (xi >= 0 && xi < W && yi >= 0 && yi < H) {
                float wgt = wx[cx] * wy[cy];
                int idx = yi * W + xi;
                atomicAdd(denb + idx, wgt);
                atomicAdd(outb + idx, v0 * wgt);
                atomicAdd(outb + N + idx, v1 * wgt);
                atomicAdd(outb + 2 * N + idx, v2 * wgt);
            }
        }
    }
}

// Normalize: out[b,c,i] /= max(den[b,i], EPS), vectorized float4.
__global__ __launch_bounds__(256) void normalize_kernel(
    float* __restrict__ out,        // [B,C,N]
    const float* __restrict__ den)  // [B,N]
{
    int t = blockIdx.x * blockDim.x + threadIdx.x;  // over (B*C*N)/4
    int total = (B * C * N) / 4;
    if (t >= total) return;

    int elem = t * 4;
    int b = elem / (C * N);
    int i = elem & (N - 1);  // elem % N

    float4 v = ((const float4*)out)[t];
    const float4 d = *(const float4*)(den + (size_t)b * N + i);
    v.x /= fmaxf(d.x, EPS);
    v.y /= fmaxf(d.y, EPS);
    v.z /= fmaxf(d.z, EPS);
    v.w /= fmaxf(d.w, EPS);
    ((float4*)out)[t] = v;
}

extern "C" void kernel_launch(void* const* d_in, const int* in_sizes, int n_in,
                              void* d_out, int out_size, void* d_ws, size_t ws_size,
                              hipStream_t stream) {
    const float* im0 = (const float*)d_in[0];   // [B,C,H,W] fp32
    const float* grid = (const float*)d_in[1];  // [B,H,W,2] fp32
    float* out = (float*)d_out;                 // [B,C,H,W] fp32
    float* den = (float*)d_ws;                  // [B,N] fp32 accumulator

    // Zero accumulators (d_out/d_ws are poisoned 0xAA before every launch).
    hipMemsetAsync(d_out, 0, (size_t)out_size * sizeof(float), stream);
    hipMemsetAsync(d_ws, 0, (size_t)B * N * sizeof(float), stream);

    {
        int threads = 256;
        int blocks = (B * N + threads - 1) / threads;
        splat_kernel<<<blocks, threads, 0, stream>>>(im0, grid, out, den);
    }
    {
        int total = (B * C * N) / 4;
        int threads = 256;
        int blocks = (total + threads - 1) / threads;
        normalize_kernel<<<blocks, threads, 0, stream>>>(out, den);
    }
}

// Round 2
// 489.966 us; speedup vs baseline: 3.7585x; 3.7585x over previous
//
#include <hip/hip_runtime.h>

// Problem constants (from reference setup_inputs)
#define B 4
#define C 3
#define H 1024
#define W 1024
#define N (H * W)
#define EPS 1e-8f

// LDS-privatized tiling for the splat.
// Each block owns a TW x TH output tile plus an R-pixel halo; contributions
// within the window go to LDS (fast ds_add_f32, planar layout = conflict-free),
// the rare >4-sigma outliers fall back to direct global atomics.
#define TW 64
#define TH 32
#define R 8
#define LW (TW + 2 * R)   // 80
#define LH (TH + 2 * R)   // 48
#define LCELLS (LW * LH)  // 3840 cells -> 4 planes * 15360 B = 60 KB LDS

__global__ __launch_bounds__(512) void splat_tiled(
    const float* __restrict__ im0,   // [B,C,H,W]
    const float* __restrict__ grid,  // [B,H,W,2]
    float* __restrict__ out,         // [B,C,H,W] numerator accumulator (pre-zeroed)
    float* __restrict__ den)         // [B,H,W]  denominator accumulator (pre-zeroed)
{
    __shared__ float sden[LCELLS];
    __shared__ float sc0[LCELLS];
    __shared__ float sc1[LCELLS];
    __shared__ float sc2[LCELLS];

    const int bid = blockIdx.x;
    const int b = bid >> 9;          // 512 tiles per batch image
    const int t = bid & 511;
    const int tx0 = (t & 15) * TW;   // 16 tiles across W
    const int ty0 = (t >> 4) * TH;   // 32 tiles down H
    const int tid = threadIdx.x;

    // Zero the LDS planes.
    for (int i = tid; i < LCELLS; i += 512) {
        sden[i] = 0.f; sc0[i] = 0.f; sc1[i] = 0.f; sc2[i] = 0.f;
    }
    __syncthreads();

    const int lx0 = tx0 - R;
    const int ly0 = ty0 - R;

    const float*  imb  = im0  + (size_t)b * C * N;
    const float2* gb   = (const float2*)(grid + (size_t)b * N * 2);
    float*        outb = out  + (size_t)b * C * N;
    float*        denb = den  + (size_t)b * N;

    const int xl = tid & 63;         // 0..63 across tile width
    const int x  = tx0 + xl;

    for (int yy = (tid >> 6); yy < TH; yy += 8) {
        const int y = ty0 + yy;
        const int n = y * W + x;

        const float2 g = gb[n];      // coalesced float2
        const float v0 = imb[n];
        const float v1 = imb[N + n];
        const float v2 = imb[2 * N + n];

        const float x0f = floorf(g.x);
        const float y0f = floorf(g.y);
        const float dx = g.x - x0f;
        const float dy = g.y - y0f;
        const int x0 = (int)x0f;
        const int y0 = (int)y0f;

        const float wxa[2] = {1.f - dx, dx};
        const float wya[2] = {1.f - dy, dy};

#pragma unroll
        for (int cy = 0; cy < 2; ++cy) {
#pragma unroll
            for (int cx = 0; cx < 2; ++cx) {
                const int xi = x0 + cx;
                const int yi = y0 + cy;
                if (xi >= 0 && xi < W && yi >= 0 && yi < H) {
                    const float wgt = wxa[cx] * wya[cy];
                    const int lx = xi - lx0;
                    const int ly = yi - ly0;
                    if ((unsigned)lx < LW && (unsigned)ly < LH) {
                        const int li = ly * LW + lx;
                        atomicAdd(&sden[li], wgt);
                        atomicAdd(&sc0[li], v0 * wgt);
                        atomicAdd(&sc1[li], v1 * wgt);
                        atomicAdd(&sc2[li], v2 * wgt);
                    } else {
                        // >4-sigma outlier: direct global fallback (rare)
                        const int gi = yi * W + xi;
                        atomicAdd(denb + gi, wgt);
                        atomicAdd(outb + gi, v0 * wgt);
                        atomicAdd(outb + N + gi, v1 * wgt);
                        atomicAdd(outb + 2 * N + gi, v2 * wgt);
                    }
                }
            }
        }
    }
    __syncthreads();

    // Flush LDS planes to global with coalesced atomics; skip all-zero cells.
    for (int i = tid; i < LCELLS; i += 512) {
        const float dsum = sden[i];
        if (dsum != 0.f) {
            const int cy = i / LW;
            const int cx = i - cy * LW;
            const int gx = lx0 + cx;
            const int gy = ly0 + cy;
            if ((unsigned)gx < W && (unsigned)gy < H) {
                const int gi = gy * W + gx;
                atomicAdd(denb + gi, dsum);
                atomicAdd(outb + gi, sc0[i]);
                atomicAdd(outb + N + gi, sc1[i]);
                atomicAdd(outb + 2 * N + gi, sc2[i]);
            }
        }
    }
}

// Normalize: out[b,c,i] /= max(den[b,i], EPS), vectorized float4.
__global__ __launch_bounds__(256) void normalize_kernel(
    float* __restrict__ out,        // [B,C,N]
    const float* __restrict__ den)  // [B,N]
{
    int t = blockIdx.x * blockDim.x + threadIdx.x;  // over (B*C*N)/4
    int total = (B * C * N) / 4;
    if (t >= total) return;

    int elem = t * 4;
    int b = elem / (C * N);
    int i = elem & (N - 1);  // elem % N

    float4 v = ((const float4*)out)[t];
    const float4 d = *(const float4*)(den + (size_t)b * N + i);
    v.x /= fmaxf(d.x, EPS);
    v.y /= fmaxf(d.y, EPS);
    v.z /= fmaxf(d.z, EPS);
    v.w /= fmaxf(d.w, EPS);
    ((float4*)out)[t] = v;
}

extern "C" void kernel_launch(void* const* d_in, const int* in_sizes, int n_in,
                              void* d_out, int out_size, void* d_ws, size_t ws_size,
                              hipStream_t stream) {
    const float* im0 = (const float*)d_in[0];   // [B,C,H,W] fp32
    const float* grid = (const float*)d_in[1];  // [B,H,W,2] fp32
    float* out = (float*)d_out;                 // [B,C,H,W] fp32
    float* den = (float*)d_ws;                  // [B,N] fp32 accumulator

    // Zero accumulators (d_out/d_ws are poisoned 0xAA before every launch).
    hipMemsetAsync(d_out, 0, (size_t)out_size * sizeof(float), stream);
    hipMemsetAsync(d_ws, 0, (size_t)B * N * sizeof(float), stream);

    {
        // 16 x 32 tiles per image, B images
        int blocks = 16 * 32 * B;
        splat_tiled<<<blocks, 512, 0, stream>>>(im0, grid, out, den);
    }
    {
        int total = (B * C * N) / 4;
        int threads = 256;
        int blocks = (total + threads - 1) / threads;
        normalize_kernel<<<blocks, threads, 0, stream>>>(out, den);
    }
}

// Round 3
// 453.151 us; speedup vs baseline: 4.0639x; 1.0812x over previous
//
#include <hip/hip_runtime.h>

// Problem constants (from reference setup_inputs)
#define B 4
#define C 3
#define H 1024
#define W 1024
#define N (H * W)
#define EPS 1e-8f

// Ownership-gather tiling: each block OWNS a TWxTH output tile (exclusive),
// and gathers all source pixels in the tile + R halo window. Corners inside
// the tile -> LDS atomic; flush is plain coalesced stores (no global atomics).
// (source,corner) pairs whose corner-owner's window misses the source are
// appended as outlier records (exact check, no sigma assumption) and applied
// by a tiny atomic kernel afterwards.
#define TW 64
#define TH 32
#define R 8
#define WINW (TW + 2 * R)     // 80
#define WINH (TH + 2 * R)     // 48
#define WCELLS (WINW * WINH)  // 3840 source pixels per block
#define TCELLS (TW * TH)      // 2048 owned cells -> 4 planes * 8KB = 32KB LDS
#define NTX (W / TW)          // 16
#define NTY (H / TH)          // 32

struct OutlierRec { int idx; float dw, d0, d1, d2; };  // idx = b*N + cell

__global__ __launch_bounds__(512) void splat_gather(
    const float* __restrict__ im0,   // [B,C,H,W]
    const float* __restrict__ grid,  // [B,H,W,2]
    float* __restrict__ out,         // [B,C,H,W] numerators (fully overwritten)
    float* __restrict__ den,         // [B,N] denominators (fully overwritten)
    int* __restrict__ counter,       // outlier count (pre-zeroed)
    OutlierRec* __restrict__ recs,   // outlier records
    int cap)
{
    __shared__ float sden[TCELLS];
    __shared__ float sc0[TCELLS];
    __shared__ float sc1[TCELLS];
    __shared__ float sc2[TCELLS];

    const int bid = blockIdx.x;
    const int b = bid >> 9;            // NTX*NTY = 512 tiles per image
    const int t = bid & 511;
    const int tx0 = (t & (NTX - 1)) * TW;
    const int ty0 = (t >> 4) * TH;
    const int tid = threadIdx.x;

    // Zero LDS planes: 2048 cells / 512 threads = 1 float4 per plane each.
    {
        float4 z = make_float4(0.f, 0.f, 0.f, 0.f);
        ((float4*)sden)[tid] = z;
        ((float4*)sc0)[tid] = z;
        ((float4*)sc1)[tid] = z;
        ((float4*)sc2)[tid] = z;
    }
    __syncthreads();

    const int lx0 = tx0 - R;
    const int ly0 = ty0 - R;

    const float*  imb = im0 + (size_t)b * C * N;
    const float2* gb  = (const float2*)(grid + (size_t)b * N * 2);

    for (int i = tid; i < WCELLS; i += 512) {
        const int wy = i / WINW;
        const int wx = i - wy * WINW;
        const int sx = lx0 + wx;
        const int sy = ly0 + wy;
        if ((unsigned)sx >= W || (unsigned)sy >= H) continue;

        const int n = sy * W + sx;
        const float2 g = gb[n];
        const float v0 = imb[n];
        const float v1 = imb[N + n];
        const float v2 = imb[2 * N + n];

        const float x0f = floorf(g.x);
        const float y0f = floorf(g.y);
        const float dx = g.x - x0f;
        const float dy = g.y - y0f;
        const int x0 = (int)x0f;
        const int y0 = (int)y0f;

        const float wxa[2] = {1.f - dx, dx};
        const float wya[2] = {1.f - dy, dy};

        const bool src_owner = ((unsigned)(sx - tx0) < TW) && ((unsigned)(sy - ty0) < TH);

#pragma unroll
        for (int cy = 0; cy < 2; ++cy) {
#pragma unroll
            for (int cx = 0; cx < 2; ++cx) {
                const int xi = x0 + cx;
                const int yi = y0 + cy;
                const int clx = xi - tx0;
                const int cly = yi - ty0;
                const float wgt = wxa[cx] * wya[cy];
                if ((unsigned)clx < TW && (unsigned)cly < TH) {
                    const int li = cly * TW + clx;
                    unsafeAtomicAdd(&sden[li], wgt);
                    unsafeAtomicAdd(&sc0[li], v0 * wgt);
                    unsafeAtomicAdd(&sc1[li], v1 * wgt);
                    unsafeAtomicAdd(&sc2[li], v2 * wgt);
                } else if (src_owner && (unsigned)xi < W && (unsigned)yi < H) {
                    // Does the corner-owner's window cover this source? (exact)
                    const int ox0 = (xi >> 6) * TW;
                    const int oy0 = (yi >> 5) * TH;
                    const bool covered = (sx >= ox0 - R) && (sx < ox0 + TW + R) &&
                                         (sy >= oy0 - R) && (sy < oy0 + TH + R);
                    if (!covered) {
                        const int slot = atomicAdd(counter, 1);
                        if (slot < cap) {
                            OutlierRec r;
                            r.idx = b * N + yi * W + xi;
                            r.dw = wgt; r.d0 = v0 * wgt; r.d1 = v1 * wgt; r.d2 = v2 * wgt;
                            recs[slot] = r;
                        }
                    }
                }
            }
        }
    }
    __syncthreads();

    // Flush owned tile with plain coalesced float4 stores (exclusive ownership).
    {
        const int cell = tid * 4;               // 512 threads * 4 cells = 2048
        const int cly = cell >> 6;              // /TW
        const int clx = cell & (TW - 1);
        const int gi = (ty0 + cly) * W + tx0 + clx;
        float* outb = out + (size_t)b * C * N;
        ((float4*)(den + (size_t)b * N + gi))[0] = ((const float4*)sden)[tid];
        ((float4*)(outb + gi))[0]           = ((const float4*)sc0)[tid];
        ((float4*)(outb + N + gi))[0]       = ((const float4*)sc1)[tid];
        ((float4*)(outb + 2 * N + gi))[0]   = ((const float4*)sc2)[tid];
    }
}

__global__ __launch_bounds__(256) void apply_outliers(
    float* __restrict__ out,         // [B,C,N]
    float* __restrict__ den,         // [B,N]
    const int* __restrict__ counter,
    const OutlierRec* __restrict__ recs,
    int cap)
{
    const int count = min(*counter, cap);
    for (int i = blockIdx.x * blockDim.x + threadIdx.x; i < count;
         i += gridDim.x * blockDim.x) {
        OutlierRec r = recs[i];
        const int b = r.idx >> 20;          // idx / N
        const int cell = r.idx & (N - 1);
        float* outb = out + (size_t)b * C * N + cell;
        unsafeAtomicAdd(&den[r.idx], r.dw);
        unsafeAtomicAdd(outb, r.d0);
        unsafeAtomicAdd(outb + N, r.d1);
        unsafeAtomicAdd(outb + 2 * N, r.d2);
    }
}

// Normalize: out[b,c,i] /= max(den[b,i], EPS), vectorized float4.
__global__ __launch_bounds__(256) void normalize_kernel(
    float* __restrict__ out,        // [B,C,N]
    const float* __restrict__ den)  // [B,N]
{
    int t = blockIdx.x * blockDim.x + threadIdx.x;  // over (B*C*N)/4
    int total = (B * C * N) / 4;
    if (t >= total) return;

    int elem = t * 4;
    int b = elem / (C * N);
    int i = elem & (N - 1);  // elem % N

    float4 v = ((const float4*)out)[t];
    const float4 d = *(const float4*)(den + (size_t)b * N + i);
    v.x /= fmaxf(d.x, EPS);
    v.y /= fmaxf(d.y, EPS);
    v.z /= fmaxf(d.z, EPS);
    v.w /= fmaxf(d.w, EPS);
    ((float4*)out)[t] = v;
}

extern "C" void kernel_launch(void* const* d_in, const int* in_sizes, int n_in,
                              void* d_out, int out_size, void* d_ws, size_t ws_size,
                              hipStream_t stream) {
    const float* im0 = (const float*)d_in[0];   // [B,C,H,W] fp32
    const float* grid = (const float*)d_in[1];  // [B,H,W,2] fp32
    float* out = (float*)d_out;                 // [B,C,H,W] fp32

    // d_ws layout: [0,4): outlier counter | [1024, 1024+16MB): den | records
    int* counter = (int*)d_ws;
    float* den = (float*)((char*)d_ws + 1024);
    const size_t rec_off = 1024 + (size_t)B * N * sizeof(float);
    OutlierRec* recs = (OutlierRec*)((char*)d_ws + rec_off);
    long long cap_ll = 0;
    if (ws_size > rec_off) cap_ll = (long long)((ws_size - rec_off) / sizeof(OutlierRec));
    int cap = (int)(cap_ll > (1 << 20) ? (1 << 20) : cap_ll);

    hipMemsetAsync(counter, 0, sizeof(int), stream);  // only the counter

    {
        int blocks = NTX * NTY * B;  // 2048
        splat_gather<<<blocks, 512, 0, stream>>>(im0, grid, out, den, counter, recs, cap);
    }
    apply_outliers<<<128, 256, 0, stream>>>(out, den, counter, recs, cap);
    {
        int total = (B * C * N) / 4;
        normalize_kernel<<<(total + 255) / 256, 256, 0, stream>>>(out, den);
    }
}